// Round 1
// baseline (2344.641 us; speedup 1.0000x reference)
//
#include <hip/hip_runtime.h>
#include <hip/hip_bf16.h>

// Problem constants
#define BB 2
#define SS 2048
#define DD 1024
#define HH 16
#define DHH 64
#define NN (BB*SS)   // 4096

// ---------------- GEMM: C[n,j] = sum_d A[n,d]*W[j,d] + bias[j] ----------------
// A: (NN, DD) row-major. W: (DD, DD) row-major (torch Linear weight).
// mode 0: plain store to out[n*DD + j]
// mode 1: head-split store to out[((b*HH+h)*SS + s)*DHH + dh], j = h*DHH+dh
#define BM 64
#define BN 64
#define BK 16

__global__ __launch_bounds__(256) void gemm_nt_bias(
    const float* __restrict__ A, const float* __restrict__ W,
    const float* __restrict__ bias, float* __restrict__ out, int mode) {
  __shared__ __align__(16) float As[BK][BM + 4];  // transposed: As[k][m]
  __shared__ __align__(16) float Bs[BK][BN + 4];  // Bs[k][j]
  const int t  = threadIdx.x;
  const int tx = t & 15, ty = t >> 4;
  const int m0 = blockIdx.y * BM;
  const int n0 = blockIdx.x * BN;

  float acc[4][4] = {};

  for (int k0 = 0; k0 < DD; k0 += BK) {
#pragma unroll
    for (int r = 0; r < 4; ++r) {
      int idx = t + 256 * r;          // 0..1023
      int row = idx >> 4;             // 0..63
      int col = idx & 15;             // 0..15
      As[col][row] = A[(size_t)(m0 + row) * DD + k0 + col];
      Bs[col][row] = W[(size_t)(n0 + row) * DD + k0 + col];
    }
    __syncthreads();
#pragma unroll
    for (int kk = 0; kk < BK; ++kk) {
      float4 av = *(const float4*)&As[kk][ty * 4];
      float4 bv = *(const float4*)&Bs[kk][tx * 4];
      float aarr[4] = {av.x, av.y, av.z, av.w};
      float barr[4] = {bv.x, bv.y, bv.z, bv.w};
#pragma unroll
      for (int im = 0; im < 4; ++im)
#pragma unroll
        for (int in = 0; in < 4; ++in)
          acc[im][in] += aarr[im] * barr[in];
    }
    __syncthreads();
  }

  // epilogue
  const int jbase = n0 + tx * 4;
  float4 bvec = *(const float4*)&bias[jbase];
  float barr[4] = {bvec.x, bvec.y, bvec.z, bvec.w};
#pragma unroll
  for (int im = 0; im < 4; ++im) {
    int n = m0 + ty * 4 + im;
    float4 res;
    res.x = acc[im][0] + barr[0];
    res.y = acc[im][1] + barr[1];
    res.z = acc[im][2] + barr[2];
    res.w = acc[im][3] + barr[3];
    if (mode == 0) {
      *(float4*)&out[(size_t)n * DD + jbase] = res;
    } else {
      int b = n >> 11, s = n & (SS - 1);
      int h = jbase >> 6, dh = jbase & 63;
      *(float4*)&out[(((size_t)(b * HH + h) * SS) + s) * DHH + dh] = res;
    }
  }
}

// ---------------- Attention ----------------
// q,k,v in (B,H,S,Dh) fp32. One block per (bh, 16-row q tile).
// Phase 1: stream K tiles, write RAW (scaled+masked) scores to attn_g, track
//          online (m,l) per row.
// Phase 2: stream V tiles, re-read raw scores, p = exp(s-m)/l, write p to
//          attn_g (final), accumulate out_head (B,S,D plain layout).
__global__ __launch_bounds__(256) void attn_kernel(
    const float* __restrict__ q, const float* __restrict__ k,
    const float* __restrict__ v, const int* __restrict__ mask,
    float* __restrict__ attn_g, float* __restrict__ out_head) {
  const int bh = blockIdx.x;            // 0..31
  const int it = blockIdx.y;            // 0..127
  const int b  = bh >> 4;
  const int h  = bh & 15;
  const int i0 = it * 16;

  __shared__ __align__(16) float qs[16][68];
  __shared__ __align__(16) float kvs[64][68];   // K tile in phase 1, V tile in phase 2
  __shared__ __align__(16) float ps[16][68];
  __shared__ float red[16][17];
  __shared__ float mrow[16], lrow[16], nmrow[16], invl[16];

  const int t  = threadIdx.x;
  const int jq = t & 15;
  const int i  = t >> 4;                // 0..15 (row owned for score/accum work)

  // load q tile (16 x 64)
  {
    int row = t >> 4;
    int d4  = (t & 15) * 4;
    *(float4*)&qs[row][d4] =
        *(const float4*)&q[((size_t)bh * SS + i0 + row) * DHH + d4];
  }
  if (t < 16) { mrow[t] = -1e30f; lrow[t] = 0.0f; }
  __syncthreads();

  const float scale = 0.125f;  // 1/sqrt(64)
  float* arow = attn_g + ((size_t)bh * SS + i0) * SS;

  // ---------- phase 1 ----------
  for (int jt = 0; jt < 32; ++jt) {
    int j0 = jt * 64;
#pragma unroll
    for (int r = 0; r < 4; ++r) {
      int row = (t >> 4) + 16 * r;
      int d4  = (t & 15) * 4;
      *(float4*)&kvs[row][d4] =
          *(const float4*)&k[((size_t)bh * SS + j0 + row) * DHH + d4];
    }
    __syncthreads();

    float sc[4];
#pragma unroll
    for (int c = 0; c < 4; ++c) {
      int j = jq + 16 * c;
      float s = 0.0f;
#pragma unroll
      for (int d = 0; d < 64; d += 4) {
        float4 qa = *(const float4*)&qs[i][d];
        float4 kb = *(const float4*)&kvs[j][d];
        s += qa.x * kb.x + qa.y * kb.y + qa.z * kb.z + qa.w * kb.w;
      }
      s *= scale;
      if (mask[b * SS + j0 + j] == 0) s = -1e9f;
      sc[c] = s;
      arow[(size_t)i * SS + j0 + j] = s;  // raw score
    }

    // online (m, l) update
    float pm = fmaxf(fmaxf(sc[0], sc[1]), fmaxf(sc[2], sc[3]));
    red[i][jq] = pm;
    __syncthreads();
    if (t < 16) {
      float tm = red[t][0];
#pragma unroll
      for (int x = 1; x < 16; ++x) tm = fmaxf(tm, red[t][x]);
      nmrow[t] = fmaxf(mrow[t], tm);
    }
    __syncthreads();
    float nmi = nmrow[i];
    float psum = __expf(sc[0] - nmi) + __expf(sc[1] - nmi) +
                 __expf(sc[2] - nmi) + __expf(sc[3] - nmi);
    red[i][jq] = psum;
    __syncthreads();
    if (t < 16) {
      float ssum = 0.0f;
#pragma unroll
      for (int x = 0; x < 16; ++x) ssum += red[t][x];
      lrow[t] = lrow[t] * __expf(mrow[t] - nmrow[t]) + ssum;
      mrow[t] = nmrow[t];
    }
    __syncthreads();
  }

  if (t < 16) invl[t] = 1.0f / lrow[t];
  __syncthreads();

  // ---------- phase 2 ----------
  float acc[4] = {0.f, 0.f, 0.f, 0.f};
  const int di = (t & 15) * 4;  // cols owned for accumulation (row i)
  const float mi  = mrow[i];
  const float ivi = invl[i];

  for (int jt = 0; jt < 32; ++jt) {
    int j0 = jt * 64;
#pragma unroll
    for (int r = 0; r < 4; ++r) {
      int row = (t >> 4) + 16 * r;
      int d4  = (t & 15) * 4;
      *(float4*)&kvs[row][d4] =
          *(const float4*)&v[((size_t)bh * SS + j0 + row) * DHH + d4];
    }
#pragma unroll
    for (int c = 0; c < 4; ++c) {
      int j = jq + 16 * c;
      float raw = arow[(size_t)i * SS + j0 + j];
      float p = __expf(raw - mi) * ivi;
      arow[(size_t)i * SS + j0 + j] = p;   // final attn value
      ps[i][j] = p;
    }
    __syncthreads();
#pragma unroll 8
    for (int j = 0; j < 64; ++j) {
      float p = ps[i][j];
      float4 vv = *(const float4*)&kvs[j][di];
      acc[0] += p * vv.x;
      acc[1] += p * vv.y;
      acc[2] += p * vv.z;
      acc[3] += p * vv.w;
    }
    __syncthreads();
  }

  // out_head plain (B,S,D): row s=i0+i, col h*64+di
  float4 res = {acc[0], acc[1], acc[2], acc[3]};
  *(float4*)&out_head[((size_t)b * SS + i0 + i) * DD + h * DHH + di] = res;
}

// ---------------- launch ----------------
extern "C" void kernel_launch(void* const* d_in, const int* in_sizes, int n_in,
                              void* d_out, int out_size, void* d_ws, size_t ws_size,
                              hipStream_t stream) {
  const float* Q   = (const float*)d_in[0];
  const float* K   = (const float*)d_in[1];
  const float* V   = (const float*)d_in[2];
  const int*  mask = (const int*)d_in[3];
  const float* Wq  = (const float*)d_in[4];
  const float* bq  = (const float*)d_in[5];
  const float* Wk  = (const float*)d_in[6];
  const float* bk  = (const float*)d_in[7];
  const float* Wv  = (const float*)d_in[8];
  const float* bv  = (const float*)d_in[9];
  const float* Wo  = (const float*)d_in[10];
  const float* bo  = (const float*)d_in[11];

  float* out    = (float*)d_out;                       // (B,S,D) = 4,194,304
  float* attn_g = out + (size_t)NN * DD;               // (B,H,S,S) = 134,217,728

  float* ws = (float*)d_ws;
  float* qh = ws;                                      // (B,H,S,Dh)
  float* kh = qh + (size_t)NN * DD;
  float* vh = kh + (size_t)NN * DD;
  float* oh = vh + (size_t)NN * DD;                    // (B,S,D)

  dim3 gGemm(DD / BN, NN / BM);   // (16, 64)
  dim3 bGemm(256);

  hipLaunchKernelGGL(gemm_nt_bias, gGemm, bGemm, 0, stream, Q, Wq, bq, qh, 1);
  hipLaunchKernelGGL(gemm_nt_bias, gGemm, bGemm, 0, stream, K, Wk, bk, kh, 1);
  hipLaunchKernelGGL(gemm_nt_bias, gGemm, bGemm, 0, stream, V, Wv, bv, vh, 1);

  dim3 gAttn(BB * HH, SS / 16);   // (32, 128)
  hipLaunchKernelGGL(attn_kernel, gAttn, dim3(256), 0, stream,
                     qh, kh, vh, mask, attn_g, oh);

  hipLaunchKernelGGL(gemm_nt_bias, gGemm, bGemm, 0, stream, oh, Wo, bo, out, 0);
}